// Round 5
// baseline (739.196 us; speedup 1.0000x reference)
//
#include <hip/hip_runtime.h>
#include <math.h>

#define NTOK 131072
#define KC   1024
#define DIMV 64

#define OUT_LOSS 0
#define OUT_Q    1
#define OUT_PERP (1 + NTOK * DIMV)
#define OUT_IDX  (2 + NTOK * DIMV)

#define MARGIN 2.5e-4f   // >= 10 sigma of total comparison error (~2.3e-5)
#define FULLSENT -2000000.0f
#define XROW   72        // LDS row pitch in shorts: 64 + 8 pad

typedef __attribute__((ext_vector_type(8))) short short8;
typedef __attribute__((ext_vector_type(4))) float f32x4;

// numpy pairwise_sum mimic for n=64 of v[i]*v[i] (bit-exact vs np reference,
// verified rounds 1-4: overall absmax 0.0).
__device__ __forceinline__ float sumsq64_np(const float v[DIMV]) {
#pragma clang fp contract(off)
  {
    float r[8];
#pragma unroll
    for (int j = 0; j < 8; ++j) r[j] = v[j] * v[j];
#pragma unroll
    for (int i = 8; i < 64; i += 8) {
#pragma unroll
      for (int j = 0; j < 8; ++j) r[j] += v[i + j] * v[i + j];
    }
    return ((r[0] + r[1]) + (r[2] + r[3])) + ((r[4] + r[5]) + (r[6] + r[7]));
  }
}

// RNE bf16 hi/lo split: f ~= hi + lo
__device__ __forceinline__ void bsplit(float f, unsigned short& h, unsigned short& l) {
  unsigned int u = __float_as_uint(f);
  unsigned int r = u + 0x7fffu + ((u >> 16) & 1u);
  unsigned short hb = (unsigned short)(r >> 16);
  float fh = __uint_as_float((unsigned int)hb << 16);
  float lo = f - fh;
  unsigned int u2 = __float_as_uint(lo);
  unsigned int r2 = u2 + 0x7fffu + ((u2 >> 16) & 1u);
  h = hb;
  l = (unsigned short)(r2 >> 16);
}

// ---- prep: codebook -> bf16 hi, exact |e|^2, and fp32 TRANSPOSE cbT[d][k] --
__global__ void __launch_bounds__(256)
vq_prep_kernel(const float* __restrict__ cb, unsigned short* __restrict__ cbh,
               float* __restrict__ cbT, float* __restrict__ ee) {
  const int k = blockIdx.x * 256 + threadIdx.x;   // grid 4*256 = 1024 exact
  float e[DIMV];
  const float4* e4 = reinterpret_cast<const float4*>(cb + k * DIMV);
#pragma unroll
  for (int i = 0; i < 16; ++i) {
    float4 t = e4[i];
    e[4 * i + 0] = t.x; e[4 * i + 1] = t.y;
    e[4 * i + 2] = t.z; e[4 * i + 3] = t.w;
  }
  ee[k] = sumsq64_np(e);
#pragma unroll
  for (int i = 0; i < DIMV; ++i) {
    unsigned short h, l;
    bsplit(e[i], h, l);
    cbh[k * DIMV + i] = h;
    cbT[i * KC + k] = e[i];          // coalesced across k
  }
}

// ---- phase A: 2-pass MFMA scores, per-token top-3 vals + top-2 idx --------
// top-3 insert (order-free set semantics; all selects read OLD values)
__device__ __forceinline__ void upd3(float& m1, float& m2, float& m3,
                                     int& i1, int& i2, float s, int c) {
  bool l1 = s < m1, l2 = s < m2, l3 = s < m3;
  m3 = l2 ? m2 : (l3 ? s : m3);
  m2 = l1 ? m1 : (l2 ? s : m2);
  i2 = l1 ? i1 : (l2 ? c : i2);
  m1 = l1 ? s : m1;
  i1 = l1 ? c : i1;
}

__global__ void __launch_bounds__(256, 4)
vq_mfma_kernel(const float* __restrict__ xin, const unsigned short* __restrict__ cbh,
               const float* __restrict__ ee, float* __restrict__ out) {
  __shared__ unsigned short sXh[64 * XROW];   // 9216 B
  __shared__ unsigned short sXl[64 * XROW];   // 9216 B
  __shared__ unsigned short sEh[128 * XROW];  // 18432 B
  __shared__ float sEe[128];                  // total ~37.4 KB -> 4 blocks/CU

  const int tid = threadIdx.x;
  const int tokenBase = blockIdx.x * 64;

  // Stage + split X (hi AND lo kept: passes are xh*eh + xl*eh).
  for (int fg = tid; fg < 512; fg += 256) {
    int tok = fg >> 3, piece = fg & 7;
    const float4* src =
        reinterpret_cast<const float4*>(xin + (tokenBase + tok) * DIMV + piece * 8);
    float4 u = src[0], v = src[1];
    float xs[8] = {u.x, u.y, u.z, u.w, v.x, v.y, v.z, v.w};
    short8 hh, ll;
#pragma unroll
    for (int i = 0; i < 8; ++i) {
      unsigned short h, l;
      bsplit(xs[i], h, l);
      hh[i] = (short)h; ll[i] = (short)l;
    }
    *(short8*)&sXh[tok * XROW + piece * 8] = hh;
    *(short8*)&sXl[tok * XROW + piece * 8] = ll;
  }
  __syncthreads();

  const int lane = tid & 63, wave = tid >> 6;
  const int q = lane >> 4, n16 = lane & 15;
  const int arow = wave * 16 + n16;

  short8 axh0 = *(const short8*)&sXh[arow * XROW + 0 + q * 8];
  short8 axh1 = *(const short8*)&sXh[arow * XROW + 32 + q * 8];
  short8 axl0 = *(const short8*)&sXl[arow * XROW + 0 + q * 8];
  short8 axl1 = *(const short8*)&sXl[arow * XROW + 32 + q * 8];

  float m1a[4], m2a[4], m3a[4];
  int i1a[4], i2a[4];
#pragma unroll
  for (int r = 0; r < 4; ++r) {
    m1a[r] = 1e30f; m2a[r] = 1e30f; m3a[r] = 1e30f; i1a[r] = 0; i2a[r] = 0;
  }

#pragma unroll 1
  for (int ch = 0; ch < 8; ++ch) {
    __syncthreads();
    const int cbase = ch * 128;
    for (int fg = tid; fg < 1024; fg += 256) {   // 128 rows x 8 pieces (hi only)
      int row = fg >> 3, piece = fg & 7;
      *(short8*)&sEh[row * XROW + piece * 8] =
          *(const short8*)&cbh[(cbase + row) * DIMV + piece * 8];
    }
    if (tid < 128) sEe[tid] = ee[cbase + tid];
    __syncthreads();

#pragma unroll 1
    for (int t = 0; t < 8; t += 2) {
      const int c0 = (t + 0) * 16 + n16;
      const int c1 = (t + 1) * 16 + n16;
      short8 b0h0 = *(const short8*)&sEh[c0 * XROW + 0 + q * 8];
      short8 b0h1 = *(const short8*)&sEh[c0 * XROW + 32 + q * 8];
      short8 b1h0 = *(const short8*)&sEh[c1 * XROW + 0 + q * 8];
      short8 b1h1 = *(const short8*)&sEh[c1 * XROW + 32 + q * 8];
      f32x4 acc0 = {0.0f, 0.0f, 0.0f, 0.0f};
      f32x4 acc1 = {0.0f, 0.0f, 0.0f, 0.0f};
      acc0 = __builtin_amdgcn_mfma_f32_16x16x32_bf16(axh0, b0h0, acc0, 0, 0, 0);
      acc1 = __builtin_amdgcn_mfma_f32_16x16x32_bf16(axh0, b1h0, acc1, 0, 0, 0);
      acc0 = __builtin_amdgcn_mfma_f32_16x16x32_bf16(axh1, b0h1, acc0, 0, 0, 0);
      acc1 = __builtin_amdgcn_mfma_f32_16x16x32_bf16(axh1, b1h1, acc1, 0, 0, 0);
      acc0 = __builtin_amdgcn_mfma_f32_16x16x32_bf16(axl0, b0h0, acc0, 0, 0, 0);
      acc1 = __builtin_amdgcn_mfma_f32_16x16x32_bf16(axl0, b1h0, acc1, 0, 0, 0);
      acc0 = __builtin_amdgcn_mfma_f32_16x16x32_bf16(axl1, b0h1, acc0, 0, 0, 0);
      acc1 = __builtin_amdgcn_mfma_f32_16x16x32_bf16(axl1, b1h1, acc1, 0, 0, 0);

      float e0 = sEe[(t + 0) * 16 + n16];
      float e1 = sEe[(t + 1) * 16 + n16];
      const int g0 = cbase + (t + 0) * 16 + n16;
      const int g1 = cbase + (t + 1) * 16 + n16;
#pragma unroll
      for (int r = 0; r < 4; ++r) {
        float s0 = __builtin_fmaf(-2.0f, acc0[r], e0);
        upd3(m1a[r], m2a[r], m3a[r], i1a[r], i2a[r], s0, g0);
        float s1 = __builtin_fmaf(-2.0f, acc1[r], e1);
        upd3(m1a[r], m2a[r], m3a[r], i1a[r], i2a[r], s1, g1);
      }
    }
  }

  // Cross-lane top-3 merge over the 16 lanes sharing tokens (xor masks <16).
#pragma unroll
  for (int r = 0; r < 4; ++r) {
    float m1 = m1a[r], m2 = m2a[r], m3 = m3a[r];
    int i1 = i1a[r], i2 = i2a[r];
#pragma unroll
    for (int m = 1; m < 16; m <<= 1) {
      float M1 = __shfl_xor(m1, m, 64);
      float M2 = __shfl_xor(m2, m, 64);
      float M3 = __shfl_xor(m3, m, 64);
      int   I1 = __shfl_xor(i1, m, 64);
      int   I2 = __shfl_xor(i2, m, 64);
      bool l1 = M1 < m1;
      float w2 = l1 ? M2 : m2;  int w2i = l1 ? I2 : i2;  // winner's 2nd
      float w3 = l1 ? M3 : m3;                           // winner's 3rd
      float z1 = l1 ? m1 : M1;  int z1i = l1 ? i1 : I1;  // loser's 1st
      float z2 = l1 ? m2 : M2;                           // loser's 2nd
      m1 = l1 ? M1 : m1;
      i1 = l1 ? I1 : i1;
      bool l2 = w2 < z1;
      m2 = l2 ? w2 : z1;
      i2 = l2 ? w2i : z1i;
      m3 = l2 ? fminf(w3, z1) : fminf(w2, z2);
    }
    if (n16 == 0) {
      int tok = tokenBase + wave * 16 + q * 4 + r;
      float outv;
      if (m2 > m1 + MARGIN) outv = (float)i1;                       // proven
      else if (m3 > m1 + MARGIN) outv = -(float)(1 + i1 * KC + i2); // 2-cand
      else outv = FULLSENT;                                         // full
      out[OUT_IDX + tok] = outv;
    }
  }
}

// ---- phase B: 2-cand exact rescore (per-lane) + full rescan (per-wave) ----
__global__ void __launch_bounds__(256)
vq_fix_kernel(const float* __restrict__ xin, const float* __restrict__ cbT,
              const float* __restrict__ ee, float* __restrict__ out) {
  const int lane = threadIdx.x & 63;
  const int gwave = (blockIdx.x * 256 + threadIdx.x) >> 6;   // [0,1024)

#pragma unroll 1
  for (int it = 0; it < 2; ++it) {
    const int base = (gwave * 2 + it) * 64;
    float f = out[OUT_IDX + base + lane];      // coalesced

    // --- 2-candidate exact rescore (reference arithmetic), per-lane ---
    if (f < 0.0f && f > -1.5e6f) {
      int n = (int)(-f) - 1;
      int i1 = n >> 10, i2 = n & (KC - 1);
      float x[DIMV];
      const float4* x4 =
          reinterpret_cast<const float4*>(xin + (long)(base + lane) * DIMV);
#pragma unroll
      for (int i = 0; i < 16; ++i) {
        float4 u = x4[i];
        x[4 * i + 0] = u.x; x[4 * i + 1] = u.y;
        x[4 * i + 2] = u.z; x[4 * i + 3] = u.w;
      }
      float xx = sumsq64_np(x);
      float d1 = 0.0f, d2 = 0.0f;
#pragma unroll
      for (int i = 0; i < DIMV; ++i)           // sequential fma, ascending i
        d1 = __builtin_fmaf(cbT[i * KC + i1], x[i], d1);
#pragma unroll
      for (int i = 0; i < DIMV; ++i)
        d2 = __builtin_fmaf(cbT[i * KC + i2], x[i], d2);
      float dd1 = (xx - 2.0f * d1) + ee[i1];   // exact reference expression
      float dd2 = (xx - 2.0f * d2) + ee[i2];
      bool t2 = (dd2 < dd1) || (dd2 == dd1 && i2 < i1);  // first-occurrence
      out[OUT_IDX + base + lane] = (float)(t2 ? i2 : i1);
    }

    // --- full rescan, wave-cooperative, coalesced via cbT ---
    unsigned long long mask = __ballot(f < -1.5e6f);
    while (mask) {
      const int b = __ffsll((long long)mask) - 1;
      mask &= mask - 1;
      const int t = base + b;                  // wave-uniform

      float x[DIMV];
      const float4* x4 = reinterpret_cast<const float4*>(xin + (long)t * DIMV);
#pragma unroll
      for (int i = 0; i < 16; ++i) {
        float4 u = x4[i];
        x[4 * i + 0] = u.x; x[4 * i + 1] = u.y;
        x[4 * i + 2] = u.z; x[4 * i + 3] = u.w;
      }
      float xx = sumsq64_np(x);

      float bd = 1e30f;
      int bi = 0x7fffffff;
#pragma unroll 1
      for (int kk = 0; kk < 16; ++kk) {
        const int c = kk * 64 + lane;
        float d = 0.0f;
#pragma unroll
        for (int i = 0; i < DIMV; ++i)         // cbT: lane-consecutive loads
          d = __builtin_fmaf(cbT[i * KC + c], x[i], d);
        float dd = (xx - 2.0f * d) + ee[c];
        bool tk = (dd < bd) || (dd == bd && c < bi);
        bd = tk ? dd : bd;
        bi = tk ? c : bi;
      }
#pragma unroll
      for (int m = 1; m < 64; m <<= 1) {
        float od = __shfl_xor(bd, m, 64);
        int   oi = __shfl_xor(bi, m, 64);
        bool take = (od < bd) || (od == bd && oi < bi);
        bd = take ? od : bd;
        bi = take ? oi : bi;
      }
      if (lane == 0) out[OUT_IDX + t] = (float)bi;
    }
  }
}

// ---- epilogue: gather/quantize/mse/hist (round-2 proven) ------------------
__global__ void __launch_bounds__(256)
vq_epilogue_kernel(const float* __restrict__ xin, const float* __restrict__ cb,
                   float* __restrict__ out, float* __restrict__ ws_mse,
                   unsigned int* __restrict__ ws_hist) {
  __shared__ unsigned int s_hist[KC];
  __shared__ float s_red[256];
  __shared__ int s_bidx[256];
  const int tid = threadIdx.x;
  for (int k = tid; k < KC; k += 256) s_hist[k] = 0u;
  __syncthreads();

  const int token = blockIdx.x * 256 + tid;
  const int bidx = (int)out[OUT_IDX + token];
  s_bidx[tid] = bidx;
  atomicAdd(&s_hist[bidx], 1u);
  __syncthreads();

  const float* xblk = xin + (size_t)blockIdx.x * (256 * DIMV);
  float* oq = out + OUT_Q + (size_t)blockIdx.x * (256 * DIMV);
  float acc = 0.0f;
#pragma unroll 4
  for (int j = 0; j < 64; ++j) {
    int g = tid + 256 * j;
    int tl = g >> 6;
    int dim = g & 63;
    float xv = xblk[g];
    float ev = cb[(long)s_bidx[tl] * DIMV + dim];
    float dmx = ev - xv;
    float qst = xv + dmx;
    acc = __builtin_fmaf(dmx, dmx, acc);
    oq[g] = qst;
  }

  s_red[tid] = acc;
  __syncthreads();
#pragma unroll
  for (int s = 128; s > 0; s >>= 1) {
    if (tid < s) s_red[tid] += s_red[tid + s];
    __syncthreads();
  }
  if (tid == 0) atomicAdd(ws_mse, s_red[0]);

  for (int k = tid; k < KC; k += 256) {
    unsigned int c = s_hist[k];
    if (c) atomicAdd(&ws_hist[k], c);
  }
}

__global__ void __launch_bounds__(1024)
vq_final_kernel(const unsigned int* __restrict__ ws_hist,
                const float* __restrict__ ws_mse, float* __restrict__ out) {
  __shared__ float s_red[1024];
  const int t = threadIdx.x;
  float p = (float)ws_hist[t] / 131072.0f;
  float term = p * logf(p + 1e-10f);
  s_red[t] = term;
  __syncthreads();
#pragma unroll
  for (int s = 512; s > 0; s >>= 1) {
    if (t < s) s_red[t] += s_red[t + s];
    __syncthreads();
  }
  if (t == 0) {
    out[OUT_PERP] = expf(-s_red[0]);
    float mse = ws_mse[0] / 8388608.0f;
    out[OUT_LOSS] = mse + 0.25f * mse;
  }
}

extern "C" void kernel_launch(void* const* d_in, const int* in_sizes, int n_in,
                              void* d_out, int out_size, void* d_ws, size_t ws_size,
                              hipStream_t stream) {
  (void)in_sizes; (void)n_in; (void)out_size; (void)ws_size;
  const float* xin = (const float*)d_in[0];
  const float* cb  = (const float*)d_in[1];
  float* out = (float*)d_out;

  char* wsb = (char*)d_ws;
  float* ws_mse = (float*)wsb;                              // [0,4)
  unsigned int* ws_hist = (unsigned int*)(wsb + 4);         // [4,4100)
  float* ws_ee = (float*)(wsb + 4352);                      // [4352,8448)
  unsigned short* ws_cbh = (unsigned short*)(wsb + 8448);   // [8448,139520)
  float* ws_cbT = (float*)(wsb + 139776);                   // [139776,401920)

  hipMemsetAsync(d_ws, 0, 4100, stream);
  hipLaunchKernelGGL(vq_prep_kernel, dim3(4), dim3(256), 0, stream,
                     cb, ws_cbh, ws_cbT, ws_ee);
  hipLaunchKernelGGL(vq_mfma_kernel, dim3(NTOK / 64), dim3(256), 0, stream,
                     xin, ws_cbh, ws_ee, out);
  hipLaunchKernelGGL(vq_fix_kernel, dim3(256), dim3(256), 0, stream,
                     xin, ws_cbT, ws_ee, out);
  hipLaunchKernelGGL(vq_epilogue_kernel, dim3(NTOK / 256), dim3(256), 0, stream,
                     xin, cb, out, ws_mse, ws_hist);
  hipLaunchKernelGGL(vq_final_kernel, dim3(1), dim3(1024), 0, stream,
                     ws_hist, ws_mse, out);
}